// Round 8
// baseline (125.294 us; speedup 1.0000x reference)
//
#include <hip/hip_runtime.h>
#include <hip/hip_bf16.h>

#define BATCH 16
#define SEQ 2048
#define DIM 64

typedef __attribute__((ext_vector_type(8))) __bf16 bf16x8;
typedef __attribute__((ext_vector_type(8))) unsigned short u16x8;
typedef __attribute__((ext_vector_type(4))) unsigned int u32x4;
typedef __attribute__((ext_vector_type(16))) float f32x16;

#if __has_builtin(__builtin_amdgcn_exp2f)
#define EXP2F(x) __builtin_amdgcn_exp2f(x)
#else
#define EXP2F(x) __expf(0.69314718055994531f * (x))
#endif

__device__ __forceinline__ unsigned short f2bf_hw(float f) {
    __bf16 h = (__bf16)f;
    return __builtin_bit_cast(unsigned short, h);
}

__device__ __forceinline__ unsigned int pk_bf16(float lo, float hi) {
    unsigned int a = f2bf_hw(lo), b = f2bf_hw(hi);
    return a | (b << 16);
}

__device__ __forceinline__ bf16x8 ld_bf8_g(const unsigned short* p) {
    u16x8 u = *(const u16x8*)p;
    return __builtin_bit_cast(bf16x8, u);
}

// Preconvert K and V to bf16 in fragment-order tile layout. 512 blocks:
// [0,256) = K path, [256,512) = V-transpose path (parallel, not serial phases).
// K tile (b,t): [g 8][key 128][8 shorts], element = K[b][t*128+key][(g>>1)*16+(g&1)*8+j]
// V tile (b,t): [g 16][d 64][8 shorts],  element = V[b][t*128+(g>>1)*16+(g&1)*8+j][d]
__global__ __launch_bounds__(256)
void preconvert_kv(const float* __restrict__ K, const float* __restrict__ V,
                   unsigned short* __restrict__ Ks, unsigned short* __restrict__ Vts) {
    __shared__ float vt[128 * 65];
    const int tid = threadIdx.x;
    if (blockIdx.x < 256) {
        const int b = blockIdx.x >> 4;
        const int t = blockIdx.x & 15;
        const float* src = K + ((size_t)(b * SEQ + t * 128)) * DIM;
        unsigned short* dst = Ks + ((size_t)(b * 16 + t)) * 8192;
        #pragma unroll
        for (int p = 0; p < 4; ++p) {
            const int cid = p * 256 + tid;          // cid = key*8 + g
            const int key = cid >> 3, g = cid & 7;
            const int d0 = (g >> 1) * 16 + (g & 1) * 8;
            float4 x0 = *(const float4*)(src + key * DIM + d0);
            float4 x1 = *(const float4*)(src + key * DIM + d0 + 4);
            u16x8 o;
            o[0] = f2bf_hw(x0.x); o[1] = f2bf_hw(x0.y); o[2] = f2bf_hw(x0.z); o[3] = f2bf_hw(x0.w);
            o[4] = f2bf_hw(x1.x); o[5] = f2bf_hw(x1.y); o[6] = f2bf_hw(x1.z); o[7] = f2bf_hw(x1.w);
            *(u16x8*)(dst + (g * 128 + key) * 8) = o;
        }
    } else {
        const int vb = blockIdx.x - 256;
        const int b = vb >> 4;
        const int t = vb & 15;
        const float* src = V + ((size_t)(b * SEQ + t * 128)) * DIM;
        #pragma unroll
        for (int p = 0; p < 8; ++p) {
            const int f = p * 256 + tid;
            const int row = f >> 4, c4 = (f & 15) << 2;
            float4 x = *(const float4*)(src + row * DIM + c4);
            vt[row * 65 + c4 + 0] = x.x; vt[row * 65 + c4 + 1] = x.y;
            vt[row * 65 + c4 + 2] = x.z; vt[row * 65 + c4 + 3] = x.w;
        }
        __syncthreads();
        unsigned short* dst = Vts + ((size_t)(b * 16 + t)) * 8192;
        #pragma unroll
        for (int p = 0; p < 4; ++p) {
            const int cid = p * 256 + tid;          // cid = g*64 + d
            const int g = cid >> 6, d = cid & 63;
            const int k0 = (g >> 1) * 16 + (g & 1) * 8;
            u16x8 o;
            #pragma unroll
            for (int j = 0; j < 8; ++j) o[j] = f2bf_hw(vt[(k0 + j) * 65 + d]);
            *(u16x8*)(dst + (g * 64 + d) * 8) = o;
        }
    }
}

// Main: no LDS staging, no main-loop barriers. Block = 32 q-rows, 4 waves = 4
// key-quarters (split-K; linear softmax -> partials add). Operands load straight
// from pre-tiled global (coalesced dwordx4, L2-resident).
// (256,3): 168-reg unified cap -> 12 waves/CU. #pragma unroll 1 on the it-loop
// keeps the scheduling scope to 4 subtiles so demand fits WITHOUT spill
// (R5/R7 spilled because full it-unroll hoisted ~16 subtiles of operands).
__global__ __launch_bounds__(256, 3)
void attn_flash_kernel(const float* __restrict__ Q,
                       const unsigned short* __restrict__ Ks,
                       const unsigned short* __restrict__ Vts,
                       const float* __restrict__ scaling,
                       float* __restrict__ O) {
    __shared__ float comb[3 * 64 * 33];   // 25,344 B

    const int tid  = threadIdx.x;
    const int w    = tid >> 6;      // key-quarter 0..3
    const int lane = tid & 63;
    const int m    = lane & 31;     // q-index within frags
    const int h    = lane >> 5;     // k-half selector

    // XCD-aware swizzle: 2 batches per XCD -> ~2 MB working set per 4 MB L2
    const int x  = blockIdx.x;
    const int b  = ((x & 7) << 1) | ((x >> 3) & 1);
    const int q0 = (x >> 4) * 32;

    const float csc = 1.4426950408889634f / scaling[0];  // log2(e)/sqrt(D)

    // Q fragments, B-layout: lane (m,h) holds Q[q0+m][c*16+h*8+{0..7}] * csc
    bf16x8 aq[4];
    {
        const float* qsrc = Q + ((size_t)(b * SEQ + q0 + m)) * DIM + h * 8;
        #pragma unroll
        for (int c = 0; c < 4; ++c) {
            float4 x0 = *(const float4*)(qsrc + c * 16);
            float4 x1 = *(const float4*)(qsrc + c * 16 + 4);
            u32x4 pk;
            pk[0] = pk_bf16(x0.x * csc, x0.y * csc);
            pk[1] = pk_bf16(x0.z * csc, x0.w * csc);
            pk[2] = pk_bf16(x1.x * csc, x1.y * csc);
            pk[3] = pk_bf16(x1.z * csc, x1.w * csc);
            aq[c] = __builtin_bit_cast(bf16x8, pk);
        }
    }

    f32x16 Oacc[2];
    #pragma unroll
    for (int dt = 0; dt < 2; ++dt)
        #pragma unroll
        for (int r = 0; r < 16; ++r) Oacc[dt][r] = 0.f;
    float psum = 0.f;

    const unsigned short* Kbase = Ks + ((size_t)(b * 16 + w * 4)) * 8192;
    const unsigned short* Vbase = Vts + ((size_t)(b * 16 + w * 4)) * 8192;

    #pragma unroll 1
    for (int it = 0; it < 4; ++it) {
        const unsigned short* Kt = Kbase + (size_t)it * 8192;
        const unsigned short* Vt = Vbase + (size_t)it * 8192;
        #pragma unroll
        for (int t = 0; t < 4; ++t) {
            // S^T = K Q^T : C-layout row = key-within-subtile, col = q
            f32x16 S;
            #pragma unroll
            for (int r = 0; r < 16; ++r) S[r] = 0.f;
            #pragma unroll
            for (int c = 0; c < 4; ++c) {
                bf16x8 bk = ld_bf8_g(&Kt[((c * 2 + h) * 128 + t * 32 + m) * 8]);
                S = __builtin_amdgcn_mfma_f32_32x32x16_bf16(bk, aq[c], S, 0, 0, 0);
            }
            // Hoist this subtile's V fragments: their latency is covered by exp2/pack
            bf16x8 bv[2][2];
            #pragma unroll
            for (int c2 = 0; c2 < 2; ++c2)
                #pragma unroll
                for (int dt = 0; dt < 2; ++dt)
                    bv[c2][dt] = ld_bf8_g(&Vt[(((2 * t + c2) * 2 + h) * 64 + dt * 32 + m) * 8]);
            // P = exp2(S); pack; half-wave swap -> P^T B-fragments in registers
            unsigned int d0[8], ds[8];
            float ps = 0.f;
            #pragma unroll
            for (int k = 0; k < 4; ++k) {
                float p0 = EXP2F(S[4 * k + 0]);
                float p1 = EXP2F(S[4 * k + 1]);
                float p2 = EXP2F(S[4 * k + 2]);
                float p3 = EXP2F(S[4 * k + 3]);
                ps += (p0 + p1) + (p2 + p3);
                d0[2 * k + 0] = pk_bf16(p0, p1);
                d0[2 * k + 1] = pk_bf16(p2, p3);
            }
            psum += ps;
            #pragma unroll
            for (int i = 0; i < 8; ++i) ds[i] = (unsigned int)__shfl_xor((int)d0[i], 32);
            #pragma unroll
            for (int c2 = 0; c2 < 2; ++c2) {
                u32x4 bw;
                bw[0] = h ? ds[4 * c2 + 2] : d0[4 * c2 + 0];
                bw[1] = h ? ds[4 * c2 + 3] : d0[4 * c2 + 1];
                bw[2] = h ? d0[4 * c2 + 2] : ds[4 * c2 + 0];
                bw[3] = h ? d0[4 * c2 + 3] : ds[4 * c2 + 1];
                bf16x8 pb = __builtin_bit_cast(bf16x8, bw);
                #pragma unroll
                for (int dt = 0; dt < 2; ++dt)
                    Oacc[dt] = __builtin_amdgcn_mfma_f32_32x32x16_bf16(bv[c2][dt], pb, Oacc[dt], 0, 0, 0);
            }
        }
    }

    // combine 4 key-quarters through LDS, normalize, store
    float lq = psum + __shfl_xor(psum, 32);   // full sum over this wave's keys, per q=m
    if (w > 0) {
        float* dst = comb + ((w - 1) * 64 + lane) * 33;
        #pragma unroll
        for (int dt = 0; dt < 2; ++dt)
            #pragma unroll
            for (int r = 0; r < 16; ++r) dst[dt * 16 + r] = Oacc[dt][r];
        dst[32] = lq;
    }
    __syncthreads();
    if (w == 0) {
        const float* p0 = comb + (0 * 64 + lane) * 33;
        const float* p1 = comb + (1 * 64 + lane) * 33;
        const float* p2 = comb + (2 * 64 + lane) * 33;
        const float invl = 1.0f / (lq + p0[32] + p1[32] + p2[32]);
        float* orow = O + ((size_t)(b * SEQ + q0 + m)) * DIM;
        #pragma unroll
        for (int dt = 0; dt < 2; ++dt) {
            #pragma unroll
            for (int k = 0; k < 4; ++k) {
                float4 o4;
                #pragma unroll
                for (int j = 0; j < 4; ++j) {
                    const int r = 4 * k + j;
                    ((float*)&o4)[j] = (Oacc[dt][r] + p0[dt * 16 + r] + p1[dt * 16 + r]
                                        + p2[dt * 16 + r]) * invl;
                }
                *(float4*)(orow + dt * 32 + 8 * k + 4 * h) = o4;
            }
        }
    }
}

extern "C" void kernel_launch(void* const* d_in, const int* in_sizes, int n_in,
                              void* d_out, int out_size, void* d_ws, size_t ws_size,
                              hipStream_t stream) {
    const float* Q = (const float*)d_in[0];
    const float* K = (const float*)d_in[1];
    const float* V = (const float*)d_in[2];
    const float* scaling = (const float*)d_in[3];
    float* O = (float*)d_out;

    unsigned short* Ks  = (unsigned short*)d_ws;                  // 4 MB
    unsigned short* Vts = Ks + (size_t)BATCH * 16 * 8192;         // 4 MB

    preconvert_kv<<<dim3(512), dim3(256), 0, stream>>>(K, V, Ks, Vts);
    attn_flash_kernel<<<dim3(BATCH * (SEQ / 32)), dim3(256), 0, stream>>>(Q, Ks, Vts, scaling, O);
}

// Round 9
// 104.285 us; speedup vs baseline: 1.2015x; 1.2015x over previous
//
#include <hip/hip_runtime.h>
#include <hip/hip_bf16.h>

#define BATCH 16
#define SEQ 2048
#define DIM 64

typedef __attribute__((ext_vector_type(8))) __bf16 bf16x8;
typedef __attribute__((ext_vector_type(8))) unsigned short u16x8;
typedef __attribute__((ext_vector_type(4))) unsigned int u32x4;
typedef __attribute__((ext_vector_type(16))) float f32x16;

#if __has_builtin(__builtin_amdgcn_exp2f)
#define EXP2F(x) __builtin_amdgcn_exp2f(x)
#else
#define EXP2F(x) __expf(0.69314718055994531f * (x))
#endif

__device__ __forceinline__ unsigned short f2bf_hw(float f) {
    __bf16 h = (__bf16)f;
    return __builtin_bit_cast(unsigned short, h);
}

__device__ __forceinline__ unsigned int pk_bf16(float lo, float hi) {
    unsigned int a = f2bf_hw(lo), b = f2bf_hw(hi);
    return a | (b << 16);
}

__device__ __forceinline__ bf16x8 ld_bf8_g(const unsigned short* p) {
    u16x8 u = *(const u16x8*)p;
    return __builtin_bit_cast(bf16x8, u);
}

// Preconvert K and V to bf16 in fragment-order tile layout. 512 blocks:
// [0,256) = K path, [256,512) = V-transpose path.
// K tile (b,t): [g 8][key 128][8 shorts], element = K[b][t*128+key][(g>>1)*16+(g&1)*8+j]
// V tile (b,t): [g 16][d 64][8 shorts],  element = V[b][t*128+(g>>1)*16+(g&1)*8+j][d]
__global__ __launch_bounds__(256)
void preconvert_kv(const float* __restrict__ K, const float* __restrict__ V,
                   unsigned short* __restrict__ Ks, unsigned short* __restrict__ Vts) {
    __shared__ float vt[128 * 65];
    const int tid = threadIdx.x;
    if (blockIdx.x < 256) {
        const int b = blockIdx.x >> 4;
        const int t = blockIdx.x & 15;
        const float* src = K + ((size_t)(b * SEQ + t * 128)) * DIM;
        unsigned short* dst = Ks + ((size_t)(b * 16 + t)) * 8192;
        #pragma unroll
        for (int p = 0; p < 4; ++p) {
            const int cid = p * 256 + tid;          // cid = key*8 + g
            const int key = cid >> 3, g = cid & 7;
            const int d0 = (g >> 1) * 16 + (g & 1) * 8;
            float4 x0 = *(const float4*)(src + key * DIM + d0);
            float4 x1 = *(const float4*)(src + key * DIM + d0 + 4);
            u16x8 o;
            o[0] = f2bf_hw(x0.x); o[1] = f2bf_hw(x0.y); o[2] = f2bf_hw(x0.z); o[3] = f2bf_hw(x0.w);
            o[4] = f2bf_hw(x1.x); o[5] = f2bf_hw(x1.y); o[6] = f2bf_hw(x1.z); o[7] = f2bf_hw(x1.w);
            *(u16x8*)(dst + (g * 128 + key) * 8) = o;
        }
    } else {
        const int vb = blockIdx.x - 256;
        const int b = vb >> 4;
        const int t = vb & 15;
        const float* src = V + ((size_t)(b * SEQ + t * 128)) * DIM;
        #pragma unroll
        for (int p = 0; p < 8; ++p) {
            const int f = p * 256 + tid;
            const int row = f >> 4, c4 = (f & 15) << 2;
            float4 x = *(const float4*)(src + row * DIM + c4);
            vt[row * 65 + c4 + 0] = x.x; vt[row * 65 + c4 + 1] = x.y;
            vt[row * 65 + c4 + 2] = x.z; vt[row * 65 + c4 + 3] = x.w;
        }
        __syncthreads();
        unsigned short* dst = Vts + ((size_t)(b * 16 + t)) * 8192;
        #pragma unroll
        for (int p = 0; p < 4; ++p) {
            const int cid = p * 256 + tid;          // cid = g*64 + d
            const int g = cid >> 6, d = cid & 63;
            const int k0 = (g >> 1) * 16 + (g & 1) * 8;
            u16x8 o;
            #pragma unroll
            for (int j = 0; j < 8; ++j) o[j] = f2bf_hw(vt[(k0 + j) * 65 + d]);
            *(u16x8*)(dst + (g * 64 + d) * 8) = o;
        }
    }
}

// Main: no LDS staging, no main-loop barriers. Block = 64 q-rows (2 q-sets per
// wave -> every K/V fragment feeds 4 MFMAs; 256 MB total L2 traffic), 4 waves =
// 4 key-quarters (split-K; linear softmax -> partials add).
// Flattened 16-subtile loop, unroll 1, with K-fragment prefetch one subtile
// ahead and V loads hoisted before the exp2 phase: every operand load has
// 300+ cycles of compute behind it (R8 showed exposed latency, not spill or
// pipe throughput, is the limiter).
__global__ __launch_bounds__(256, 2)
void attn_flash_kernel(const float* __restrict__ Q,
                       const unsigned short* __restrict__ Ks,
                       const unsigned short* __restrict__ Vts,
                       const float* __restrict__ scaling,
                       float* __restrict__ O) {
    __shared__ float comb[3 * 64 * 66];   // 50,688 B

    const int tid  = threadIdx.x;
    const int w    = tid >> 6;      // key-quarter 0..3
    const int lane = tid & 63;
    const int m    = lane & 31;     // q-index within frags
    const int h    = lane >> 5;     // k-half selector

    // XCD-aware swizzle: 2 batches per XCD -> ~1 MB KV working set per 4 MB L2
    const int x  = blockIdx.x;
    const int b  = ((x & 7) << 1) | ((x >> 3) & 1);
    const int q0 = (x >> 4) * 64;

    const float csc = 1.4426950408889634f / scaling[0];  // log2(e)/sqrt(D)

    // Q fragments for both q-sets, B-layout: lane (m,h) holds Q[q][c*16+h*8+{0..7}]*csc
    bf16x8 aq0[4], aq1[4];
    #pragma unroll
    for (int s = 0; s < 2; ++s) {
        const float* qsrc = Q + ((size_t)(b * SEQ + q0 + s * 32 + m)) * DIM + h * 8;
        #pragma unroll
        for (int c = 0; c < 4; ++c) {
            float4 x0 = *(const float4*)(qsrc + c * 16);
            float4 x1 = *(const float4*)(qsrc + c * 16 + 4);
            u32x4 pk;
            pk[0] = pk_bf16(x0.x * csc, x0.y * csc);
            pk[1] = pk_bf16(x0.z * csc, x0.w * csc);
            pk[2] = pk_bf16(x1.x * csc, x1.y * csc);
            pk[3] = pk_bf16(x1.z * csc, x1.w * csc);
            (s ? aq1 : aq0)[c] = __builtin_bit_cast(bf16x8, pk);
        }
    }

    f32x16 Oacc0[2], Oacc1[2];
    #pragma unroll
    for (int dt = 0; dt < 2; ++dt)
        #pragma unroll
        for (int r = 0; r < 16; ++r) { Oacc0[dt][r] = 0.f; Oacc1[dt][r] = 0.f; }
    float psum0 = 0.f, psum1 = 0.f;

    const unsigned short* Kbase = Ks + ((size_t)(b * 16 + w * 4)) * 8192;
    const unsigned short* Vbase = Vts + ((size_t)(b * 16 + w * 4)) * 8192;

    // prologue: K fragments for subtile 0
    bf16x8 kc[4];
    #pragma unroll
    for (int c = 0; c < 4; ++c)
        kc[c] = ld_bf8_g(&Kbase[((c * 2 + h) * 128 + m) * 8]);

    #pragma unroll 1
    for (int st = 0; st < 16; ++st) {
        const int it = st >> 2, t = st & 3;
        const unsigned short* Vt = Vbase + (size_t)it * 8192;

        // S^T = K Q^T for both q-sets (K fragments shared, prefetched last iter)
        f32x16 S0, S1;
        #pragma unroll
        for (int r = 0; r < 16; ++r) { S0[r] = 0.f; S1[r] = 0.f; }
        #pragma unroll
        for (int c = 0; c < 4; ++c) {
            S0 = __builtin_amdgcn_mfma_f32_32x32x16_bf16(kc[c], aq0[c], S0, 0, 0, 0);
            S1 = __builtin_amdgcn_mfma_f32_32x32x16_bf16(kc[c], aq1[c], S1, 0, 0, 0);
        }

        // prefetch next subtile's K fragments (covered by exp+shfl+PV below)
        const int stn = (st < 15) ? st + 1 : 15;
        const unsigned short* Ktn = Kbase + (size_t)(stn >> 2) * 8192;
        const int tn = stn & 3;
        bf16x8 kn[4];
        #pragma unroll
        for (int c = 0; c < 4; ++c)
            kn[c] = ld_bf8_g(&Ktn[((c * 2 + h) * 128 + tn * 32 + m) * 8]);

        // V fragments for this subtile (latency covered by exp2/pack/shfl)
        bf16x8 bv[2][2];
        #pragma unroll
        for (int c2 = 0; c2 < 2; ++c2)
            #pragma unroll
            for (int dt = 0; dt < 2; ++dt)
                bv[c2][dt] = ld_bf8_g(&Vt[(((2 * t + c2) * 2 + h) * 64 + dt * 32 + m) * 8]);

        // P = exp2(S); pack; half-wave swap -> P^T B-fragments (both sets)
        unsigned int d0a[8], d0b[8], dsa[8], dsb[8];
        #pragma unroll
        for (int k = 0; k < 4; ++k) {
            float a0 = EXP2F(S0[4 * k + 0]), a1 = EXP2F(S0[4 * k + 1]);
            float a2 = EXP2F(S0[4 * k + 2]), a3 = EXP2F(S0[4 * k + 3]);
            psum0 += (a0 + a1) + (a2 + a3);
            d0a[2 * k + 0] = pk_bf16(a0, a1);
            d0a[2 * k + 1] = pk_bf16(a2, a3);
            float b0 = EXP2F(S1[4 * k + 0]), b1 = EXP2F(S1[4 * k + 1]);
            float b2 = EXP2F(S1[4 * k + 2]), b3 = EXP2F(S1[4 * k + 3]);
            psum1 += (b0 + b1) + (b2 + b3);
            d0b[2 * k + 0] = pk_bf16(b0, b1);
            d0b[2 * k + 1] = pk_bf16(b2, b3);
        }
        #pragma unroll
        for (int i = 0; i < 8; ++i) {
            dsa[i] = (unsigned int)__shfl_xor((int)d0a[i], 32);
            dsb[i] = (unsigned int)__shfl_xor((int)d0b[i], 32);
        }
        #pragma unroll
        for (int c2 = 0; c2 < 2; ++c2) {
            u32x4 bw0, bw1;
            bw0[0] = h ? dsa[4 * c2 + 2] : d0a[4 * c2 + 0];
            bw0[1] = h ? dsa[4 * c2 + 3] : d0a[4 * c2 + 1];
            bw0[2] = h ? d0a[4 * c2 + 2] : dsa[4 * c2 + 0];
            bw0[3] = h ? d0a[4 * c2 + 3] : dsa[4 * c2 + 1];
            bw1[0] = h ? dsb[4 * c2 + 2] : d0b[4 * c2 + 0];
            bw1[1] = h ? dsb[4 * c2 + 3] : d0b[4 * c2 + 1];
            bw1[2] = h ? d0b[4 * c2 + 2] : dsb[4 * c2 + 0];
            bw1[3] = h ? d0b[4 * c2 + 3] : dsb[4 * c2 + 1];
            bf16x8 pb0 = __builtin_bit_cast(bf16x8, bw0);
            bf16x8 pb1 = __builtin_bit_cast(bf16x8, bw1);
            #pragma unroll
            for (int dt = 0; dt < 2; ++dt) {
                Oacc0[dt] = __builtin_amdgcn_mfma_f32_32x32x16_bf16(bv[c2][dt], pb0, Oacc0[dt], 0, 0, 0);
                Oacc1[dt] = __builtin_amdgcn_mfma_f32_32x32x16_bf16(bv[c2][dt], pb1, Oacc1[dt], 0, 0, 0);
            }
        }

        #pragma unroll
        for (int c = 0; c < 4; ++c) kc[c] = kn[c];
    }

    // combine 4 key-quarters through LDS, normalize, store (2 q-sets)
    float l0 = psum0 + __shfl_xor(psum0, 32);
    float l1 = psum1 + __shfl_xor(psum1, 32);
    if (w > 0) {
        float* dst = comb + ((w - 1) * 64 + lane) * 66;
        #pragma unroll
        for (int dt = 0; dt < 2; ++dt)
            #pragma unroll
            for (int r = 0; r < 16; ++r) {
                dst[dt * 16 + r]      = Oacc0[dt][r];
                dst[33 + dt * 16 + r] = Oacc1[dt][r];
            }
        dst[32] = l0;
        dst[65] = l1;
    }
    __syncthreads();
    if (w == 0) {
        const float* p0 = comb + (0 * 64 + lane) * 66;
        const float* p1 = comb + (1 * 64 + lane) * 66;
        const float* p2 = comb + (2 * 64 + lane) * 66;
        const float invl0 = 1.0f / (l0 + p0[32] + p1[32] + p2[32]);
        const float invl1 = 1.0f / (l1 + p0[65] + p1[65] + p2[65]);
        float* orow0 = O + ((size_t)(b * SEQ + q0 + m)) * DIM;
        float* orow1 = O + ((size_t)(b * SEQ + q0 + 32 + m)) * DIM;
        #pragma unroll
        for (int dt = 0; dt < 2; ++dt) {
            #pragma unroll
            for (int k = 0; k < 4; ++k) {
                float4 o4;
                #pragma unroll
                for (int j = 0; j < 4; ++j) {
                    const int r = 4 * k + j;
                    ((float*)&o4)[j] = (Oacc0[dt][r] + p0[dt * 16 + r] + p1[dt * 16 + r]
                                        + p2[dt * 16 + r]) * invl0;
                }
                *(float4*)(orow0 + dt * 32 + 8 * k + 4 * h) = o4;
                #pragma unroll
                for (int j = 0; j < 4; ++j) {
                    const int r = 4 * k + j;
                    ((float*)&o4)[j] = (Oacc1[dt][r] + p0[33 + dt * 16 + r] + p1[33 + dt * 16 + r]
                                        + p2[33 + dt * 16 + r]) * invl1;
                }
                *(float4*)(orow1 + dt * 32 + 8 * k + 4 * h) = o4;
            }
        }
    }
}

extern "C" void kernel_launch(void* const* d_in, const int* in_sizes, int n_in,
                              void* d_out, int out_size, void* d_ws, size_t ws_size,
                              hipStream_t stream) {
    const float* Q = (const float*)d_in[0];
    const float* K = (const float*)d_in[1];
    const float* V = (const float*)d_in[2];
    const float* scaling = (const float*)d_in[3];
    float* O = (float*)d_out;

    unsigned short* Ks  = (unsigned short*)d_ws;                  // 4 MB
    unsigned short* Vts = Ks + (size_t)BATCH * 16 * 8192;         // 4 MB

    preconvert_kv<<<dim3(512), dim3(256), 0, stream>>>(K, V, Ks, Vts);
    attn_flash_kernel<<<dim3(BATCH * (SEQ / 64)), dim3(256), 0, stream>>>(Q, Ks, Vts, scaling, O);
}